// Round 6
// baseline (11770.662 us; speedup 1.0000x reference)
//
#include <hip/hip_runtime.h>

typedef unsigned int uint;
typedef unsigned long long u64;
typedef _Float16 f16x2 __attribute__((ext_vector_type(2)));

#define SEQ 4096
#define EMB 300
#define HID 500
#define NG 2000      // 4*HID
#define KX 600       // 2*EMB
#define KXP 608      // padded K for aligned float4 loads

#define BM 64
#define BN 64
#define BK 16

#define NWG 25       // workgroups in recurrence
#define UPW 20       // hidden units per workgroup
#define NPOLL 64     // ONE dedicated poller wave
#define NCOMP 640    // compute threads: 20 units * 32 lanes
#define TPB (NPOLL + NCOMP)   // 704 = 11 waves

// Spin guards: healthy waits are a few iterations; these only exist so a
// pathological state terminates (wrong answer + counters) instead of wedging
// the GPU/container.  r5 proved they never fire on the healthy path.
#define FASTCAP 8
#define STEP_GUARD 4096
#define FC_GUARD   (1 << 20)

// Exchange layout (round-6 change): 500 tagged dwords (h16<<16 | tag16)
// CONTIGUOUS per step-buffer (2 KB), padded to 512 dwords.  A full-state
// poll sweep = 2 coalesced dwordx4 loads/lane x 64 lanes = 2 KB in 2 VMEM
// instructions, vs 250 scattered 64B lines (16 KB) before.  Poll requesters
// drop 6250 -> 1600 grid-wide; LLC queue contention was the round-5 lesson.
#define HBSTRIDE 512               // dwords per buffer half
#define HTOTD (2 * HBSTRIDE)       // 1024 dwords = 4 KB

// ---------------------------------------------------------------- gather x
__global__ __launch_bounds__(256) void gather_x(const int* __restrict__ words,
                                                const int* __restrict__ labels,
                                                const float* __restrict__ embw,
                                                const float* __restrict__ embe,
                                                float* __restrict__ x) {
  int t = blockIdx.x;
  int w = words[t], l = labels[t];
  const float* rw = embw + (size_t)w * EMB;
  const float* re = embe + (size_t)l * EMB;
  float* xr = x + (size_t)t * KXP;
  for (int k = threadIdx.x; k < KXP; k += 256) {
    float v = 0.f;
    if (k < EMB) v = rw[k];
    else if (k < KX) v = re[k - EMB];
    xr[k] = v;  // pads [600,608) zeroed
  }
}

// ---------------------------------------------------------------- pre GEMM
__global__ __launch_bounds__(256) void gemm_pre(const float* __restrict__ x,
                                                const float* __restrict__ Wih,
                                                const float* __restrict__ bih,
                                                const float* __restrict__ bhh,
                                                float* __restrict__ pre) {
  __shared__ float As[BK][BM + 4];
  __shared__ float Bs[BK][BN + 4];
  const int m0 = blockIdx.x * BM;
  const int n0 = blockIdx.y * BN;
  const int tid = threadIdx.x;
  const int tx = tid & 15, ty = tid >> 4;
  const int lrow = tid >> 2;          // 0..63
  const int lc4 = (tid & 3) << 2;     // 0,4,8,12
  float acc[4][4] = {};

  for (int kk = 0; kk < KX; kk += BK) {
    float4 av = *(const float4*)(x + (size_t)(m0 + lrow) * KXP + kk + lc4);
    int brow = n0 + lrow; if (brow >= NG) brow = 0;
    float4 bv;
    if (kk + lc4 + 3 < KX) {
      bv = *(const float4*)(Wih + (size_t)brow * KX + kk + lc4);
    } else {
      float tmp[4];
#pragma unroll
      for (int j = 0; j < 4; ++j) {
        int k = kk + lc4 + j;
        tmp[j] = (k < KX) ? Wih[(size_t)brow * KX + k] : 0.f;
      }
      bv = make_float4(tmp[0], tmp[1], tmp[2], tmp[3]);
    }
    As[lc4 + 0][lrow] = av.x; As[lc4 + 1][lrow] = av.y;
    As[lc4 + 2][lrow] = av.z; As[lc4 + 3][lrow] = av.w;
    Bs[lc4 + 0][lrow] = bv.x; Bs[lc4 + 1][lrow] = bv.y;
    Bs[lc4 + 2][lrow] = bv.z; Bs[lc4 + 3][lrow] = bv.w;
    __syncthreads();
#pragma unroll
    for (int k = 0; k < BK; ++k) {
      float4 a = *(const float4*)&As[k][ty << 2];
      float4 b = *(const float4*)&Bs[k][tx << 2];
      acc[0][0] += a.x * b.x; acc[0][1] += a.x * b.y; acc[0][2] += a.x * b.z; acc[0][3] += a.x * b.w;
      acc[1][0] += a.y * b.x; acc[1][1] += a.y * b.y; acc[1][2] += a.y * b.z; acc[1][3] += a.y * b.w;
      acc[2][0] += a.z * b.x; acc[2][1] += a.z * b.y; acc[2][2] += a.z * b.z; acc[2][3] += a.z * b.w;
      acc[3][0] += a.w * b.x; acc[3][1] += a.w * b.y; acc[3][2] += a.w * b.z; acc[3][3] += a.w * b.w;
    }
    __syncthreads();
  }
#pragma unroll
  for (int i = 0; i < 4; ++i) {
    int m = m0 + (ty << 2) + i;
#pragma unroll
    for (int j = 0; j < 4; ++j) {
      int n = n0 + (tx << 2) + j;
      if (n < NG) pre[(size_t)m * NG + n] = acc[i][j] + bih[n] + bhh[n];
    }
  }
}

// ---------------------------------------------------------------- sync init
__global__ void init_sync(uint* hbuf) {
  for (int i = threadIdx.x; i < HTOTD; i += 1024) hbuf[i] = 0u;
}

// ---------------------------------------------------------------- recurrence
__device__ __forceinline__ float sigm(float x) { return 1.f / (1.f + __expf(-x)); }
__device__ __forceinline__ float fast_tanh(float x) {
  x = fminf(fmaxf(x, -15.f), 15.f);
  float e = __expf(2.f * x);
  return (e - 1.f) / (e + 1.f);
}
__device__ __forceinline__ f16x2 as_f16x2(uint u) {
  union { uint i; f16x2 h; } c; c.i = u; return c.h;
}
__device__ __forceinline__ uint f2h16(float f) {
  union { _Float16 h; unsigned short u; } c; c.h = (_Float16)f; return (uint)c.u;
}
#if __has_builtin(__builtin_amdgcn_fdot2)
__device__ __forceinline__ float FDOT2(f16x2 a, f16x2 b, float c) {
  return __builtin_amdgcn_fdot2(a, b, c, false);
}
#else
__device__ __forceinline__ float FDOT2(f16x2 a, f16x2 b, float c) {
  return c + (float)a.x * (float)b.x + (float)a.y * (float)b.y;
}
#endif

// Fast leg: 32B of tagged dwords in 2 coalesced dwordx4, bypassing L1+L2
// (sc0 sc1) so the LLC-fresh value is observed.  Each dword self-tags, so
// no multi-word atomicity is required.
__device__ __forceinline__ void ldfast(const uint* p, uint4& a, uint4& b) {
  asm volatile("global_load_dwordx4 %0, %2, off sc0 sc1\n\t"
               "global_load_dwordx4 %1, %2, off offset:16 sc0 sc1\n\t"
               "s_waitcnt vmcnt(0)"
               : "=v"(a), "=v"(b) : "v"(p) : "memory");
}
__device__ __forceinline__ uint ld_agent(const uint* p) {
  return __hip_atomic_load(p, __ATOMIC_RELAXED, __HIP_MEMORY_SCOPE_AGENT);
}
__device__ __forceinline__ uint cmp8(uint4 a, uint4 b, uint want) {
  uint r = 0;
  r |= ((a.x & 0xffffu) == want) ? 1u : 0u;
  r |= ((a.y & 0xffffu) == want) ? 2u : 0u;
  r |= ((a.z & 0xffffu) == want) ? 4u : 0u;
  r |= ((a.w & 0xffffu) == want) ? 8u : 0u;
  r |= ((b.x & 0xffffu) == want) ? 16u : 0u;
  r |= ((b.y & 0xffffu) == want) ? 32u : 0u;
  r |= ((b.z & 0xffffu) == want) ? 64u : 0u;
  r |= ((b.w & 0xffffu) == want) ? 128u : 0u;
  return r;
}

// Poll one lane's 8 dwords until the valid ones carry tag `want`.
// Fast sc0-sc1 leg; after FASTCAP misses interleave the PROVEN per-dword
// agent-scope load (deadlock-proof); guard terminates pathological states.
__device__ __forceinline__ void poll8(const uint* src, uint want, uint vmask,
                                      int guard_max, uint4& va, uint4& vb) {
#pragma nounroll
  for (int it = 0; ; ++it) {
    ldfast(src, va, vb);
    if ((cmp8(va, vb, want) & vmask) == vmask) return;
    if (it >= FASTCAP) {
      uint q[8];
#pragma unroll
      for (int j = 0; j < 8; ++j) q[j] = ld_agent(src + j);
      va = make_uint4(q[0], q[1], q[2], q[3]);
      vb = make_uint4(q[4], q[5], q[6], q[7]);
      if ((cmp8(va, vb, want) & vmask) == vmask) return;
    }
    if (it > guard_max) return;   // never on healthy path (r5-proven guards)
  }
}

// Wave roles: wave 0 = poller (lane l owns dwords [8l,8l+8) of the 512-dword
// buffer), waves 1-10 = compute (identical to the proven compute structure).
__global__ __launch_bounds__(TPB) void lstm_seq(const float* __restrict__ pre,
                                                const float* __restrict__ Whh,
                                                const float* __restrict__ fcw,
                                                const float* __restrict__ fcb,
                                                uint* hbuf,
                                                float* __restrict__ out) {
  __shared__ __attribute__((aligned(16))) uint h2b[2][256];
  const int g = blockIdx.x;
  const int tid = threadIdx.x;
  const bool pwave = tid < NPOLL;            // wave-uniform split
  const int local = pwave ? 0 : tid - NPOLL; // compute index 0..639
  const int unit = local >> 5;
  const int gi = (local >> 3) & 3;
  const int cc = local & 7;
  const int owner = !pwave && ((local & 31) == 0);
  const int base = tid & 32;                 // wave-relative 32-group base
  const int my_prerow = gi * HID + g * UPW + unit;
  const int my_unit = g * UPW + unit;

  // per-poller-lane validity: dwords 8l+j with index >= HID are padding
  // (always zero, tag 0) and must be excluded from the tag check.
  int nvalid = HID - tid * 8;
  nvalid = nvalid < 0 ? 0 : (nvalid > 8 ? 8 : nvalid);
  const uint vmask = (nvalid >= 8) ? 0xffu : ((1u << nvalid) - 1u);

  // zero h2b (pad slots [250,256) of each half are read as zero h)
  for (int i = tid; i < 512; i += TPB) ((uint*)h2b)[i] = 0u;

  // stage this lane's W_hh row-slice into registers (f16 pairs) — compute only
  uint wreg[32];
  if (!pwave) {
    size_t grow = (size_t)(gi * HID + g * UPW + unit) * HID;
#pragma unroll
    for (int q = 0; q < 8; ++q) {
#pragma unroll
      for (int j = 0; j < 4; ++j) {
        int word = q * 32 + cc * 4 + j;       // packed half2 index 0..255
        int c2 = word * 2;
        float v0 = (c2 < HID) ? Whh[grow + c2] : 0.f;
        float v1 = (c2 + 1 < HID) ? Whh[grow + c2 + 1] : 0.f;
        wreg[q * 4 + j] = f2h16(v0) | (f2h16(v1) << 16);
      }
    }
  }

  float c_reg = 0.f;

  // software-pipelined pre: value for step t loaded during step t-1
  float pre_v = 0.f;
  if (!pwave && cc == 0) pre_v = pre[my_prerow];   // t = 0

  for (int t = 0; t < SEQ; ++t) {
    if (pwave) {
      const uint want = (uint)t & 0xffffu;
      const uint* src = hbuf + (size_t)(t & 1) * HBSTRIDE + tid * 8;
      uint4 va, vb;
      poll8(src, want, vmask, STEP_GUARD, va, vb);
      // repack tagged dwords -> h2 pairs (units 8l+2k, 8l+2k+1)
      uint p0 = (va.x >> 16) | (va.y & 0xffff0000u);
      uint p1 = (va.z >> 16) | (va.w & 0xffff0000u);
      uint p2 = (vb.x >> 16) | (vb.y & 0xffff0000u);
      uint p3 = (vb.z >> 16) | (vb.w & 0xffff0000u);
      *(uint4*)&h2b[t & 1][tid * 4] = make_uint4(p0, p1, p2, p3);
    }
    __syncthreads();  // one barrier per step; poll of t+1 overlaps compute of t

    if (!pwave) {
      // next step's pre row: latency hides under matvec + the concurrent poll
      float pre_nx = 0.f;
      if (cc == 0 && t + 1 < SEQ) pre_nx = pre[(size_t)(t + 1) * NG + my_prerow];

      // matvec: 8 chunks x 4 half2 from registers vs LDS h (broadcast reads)
      const uint* h2 = h2b[t & 1];
      float acc = 0.f;
#pragma unroll
      for (int q = 0; q < 8; ++q) {
        uint4 hh = *(const uint4*)&h2[q * 32 + cc * 4];
        acc = FDOT2(as_f16x2(wreg[q * 4 + 0]), as_f16x2(hh.x), acc);
        acc = FDOT2(as_f16x2(wreg[q * 4 + 1]), as_f16x2(hh.y), acc);
        acc = FDOT2(as_f16x2(wreg[q * 4 + 2]), as_f16x2(hh.z), acc);
        acc = FDOT2(as_f16x2(wreg[q * 4 + 3]), as_f16x2(hh.w), acc);
      }
      acc += __shfl_xor(acc, 1);
      acc += __shfl_xor(acc, 2);
      acc += __shfl_xor(acc, 4);
      if (cc == 0) acc += pre_v;   // cc==0 lane of each gate octet holds row sum

      // gather the 4 gate sums into the unit-owner lane (in-wave)
      float si = __shfl(acc, base + 0);
      float sf = __shfl(acc, base + 8);
      float sg = __shfl(acc, base + 16);
      float so = __shfl(acc, base + 24);
      if (owner) {
        float iv = sigm(si);
        float fv = sigm(sf);
        float gv = fast_tanh(sg);
        float ov = sigm(so);
        c_reg = fv * c_reg + iv * gv;
        float h = ov * fast_tanh(c_reg);
        uint pk = (f2h16(h) << 16) | ((uint)(t + 1) & 0xffffu);
        // proven agent-scope per-dword store (self-tagged; LLC merges bytes)
        __hip_atomic_store(hbuf + (size_t)((t + 1) & 1) * HBSTRIDE + my_unit,
                           pk, __ATOMIC_RELAXED, __HIP_MEMORY_SCOPE_AGENT);
      }
      pre_v = pre_nx;
    }
  }

  // final FC by WG 0: out = fc_w @ h_SEQ + fc_b   (h_SEQ in buffer SEQ&1 = 0)
  if (g == 0) {
    if (pwave) {
      const uint want = (uint)SEQ & 0xffffu;
      const uint* src = hbuf + tid * 8;   // buffer 0
      uint4 va, vb;
      poll8(src, want, vmask, FC_GUARD, va, vb);
      uint p0 = (va.x >> 16) | (va.y & 0xffff0000u);
      uint p1 = (va.z >> 16) | (va.w & 0xffff0000u);
      uint p2 = (vb.x >> 16) | (vb.y & 0xffff0000u);
      uint p3 = (vb.z >> 16) | (vb.w & 0xffff0000u);
      *(uint4*)&h2b[0][tid * 4] = make_uint4(p0, p1, p2, p3);
    }
    __syncthreads();
    if (!pwave) {
      int row = local >> 5, ln = local & 31;   // 20 rows x 32 lanes = 640
      float s = 0.f;
      for (int j = ln; j < HID; j += 32) {
        f16x2 p = as_f16x2(h2b[0][j >> 1]);
        float hv = (j & 1) ? (float)p.y : (float)p.x;
        s += fcw[row * HID + j] * hv;
      }
      s += __shfl_xor(s, 1); s += __shfl_xor(s, 2);
      s += __shfl_xor(s, 4); s += __shfl_xor(s, 8);
      s += __shfl_xor(s, 16);
      if (ln == 0) out[row] = s + fcb[row];
    }
  }
}

// ---------------------------------------------------------------- launch
extern "C" void kernel_launch(void* const* d_in, const int* in_sizes, int n_in,
                              void* d_out, int out_size, void* d_ws, size_t ws_size,
                              hipStream_t stream) {
  const int* words = (const int*)d_in[0];
  const int* labels = (const int*)d_in[1];
  const float* embw = (const float*)d_in[2];
  const float* embe = (const float*)d_in[3];
  const float* Wih = (const float*)d_in[4];
  const float* Whh = (const float*)d_in[5];
  const float* bih = (const float*)d_in[6];
  const float* bhh = (const float*)d_in[7];
  const float* fcw = (const float*)d_in[8];
  const float* fcb = (const float*)d_in[9];
  float* out = (float*)d_out;

  char* ws = (char*)d_ws;
  const size_t X = (size_t)SEQ * KXP * 4;       // 9.96 MB
  const size_t P = (size_t)SEQ * NG * 4;        // 32.77 MB
  float* x = (float*)ws;
  float* pre = (float*)(ws + X);
  uint* hbuf = (uint*)(ws + X + P);             // 4 KB packed tagged exchange

  gather_x<<<SEQ, 256, 0, stream>>>(words, labels, embw, embe, x);
  dim3 ggrid(SEQ / BM, (NG + BN - 1) / BN);
  gemm_pre<<<ggrid, 256, 0, stream>>>(x, Wih, bih, bhh, pre);
  init_sync<<<1, 1024, 0, stream>>>(hbuf);
  lstm_seq<<<NWG, TPB, 0, stream>>>(pre, Whh, fcw, fcb, hbuf, out);
}